// Round 1
// baseline (399.909 us; speedup 1.0000x reference)
//
#include <hip/hip_runtime.h>

// Problem constants (B, C, CI, H, W) = (4, 256, 128, 64, 64)
constexpr int kB  = 4;
constexpr int kC  = 256;
constexpr int kCI = 128;
constexpr int kN  = 64 * 64;  // 4096

// ---------------------------------------------------------------------------
// Algebraic collapse of the NonLocal2D forward:
//   out[b,o,n] = x[b,o,n] + sum_c x[b,c,n] * Mt[b,o,c] + beta[b,o]
// where (per batch):
//   Cov  = Xc * Xc^T                      (C x C gram, Xc centered over n)
//   P    = phi_w * Cov                    (CI x C)   [uses Cov symmetry]
//   S    = P * g_w^T                      (CI x CI)  (g_b drops: sum_n phi_c = 0)
//   W2t  = out_w * S^T                    (C x CI)   W2t[o,k] = sum_j S[k,j] out_w[o,j]
//   Mt   = W2t * theta_wc                 (C x C)    theta_wc = theta_w col-centered
//   beta = W2t * theta_bc + out_b
// phi_b is mathematically unused (cancelled by spatial centering).
// ---------------------------------------------------------------------------

// ws layout (floats)
constexpr long kOffXmean = 0;                       // kB*kC          = 1024
constexpr long kOffTwcT  = kOffXmean + kB * kC;     // kC*kCI         = 32768
constexpr long kOffTbc   = kOffTwcT + kC * kCI;     // kCI            = 128
constexpr long kOffCov   = kOffTbc + kCI;           // kB*kC*kC       = 262144
constexpr long kOffP     = kOffCov + kB * kC * kC;  // kB*kCI*kC      = 131072
constexpr long kOffS     = kOffP + kB * kCI * kC;   // kB*kCI*kCI     = 65536
constexpr long kOffW2t   = kOffS + kB * kCI * kCI;  // kB*kC*kCI      = 131072
constexpr long kOffMt    = kOffW2t + kB * kC * kCI; // kB*kC*kC       = 262144
constexpr long kOffBeta  = kOffMt + kB * kC * kC;   // kB*kC          = 1024
// total ~887k floats = 3.55 MB of d_ws

// ---- xmean[b,c] = mean over n of x[b,c,n] ---------------------------------
__global__ void xmean_kernel(const float* __restrict__ x, float* __restrict__ xmean) {
    int bc = blockIdx.x;  // 0 .. kB*kC-1
    const float* p = x + (long)bc * kN;
    float s = 0.f;
    for (int i = threadIdx.x; i < kN; i += 256) s += p[i];
    __shared__ float sm[256];
    sm[threadIdx.x] = s;
    __syncthreads();
    for (int st = 128; st > 0; st >>= 1) {
        if (threadIdx.x < st) sm[threadIdx.x] += sm[threadIdx.x + st];
        __syncthreads();
    }
    if (threadIdx.x == 0) xmean[bc] = sm[0] * (1.f / kN);
}

// ---- theta_w column-centered (transposed) + theta_b centered --------------
__global__ void centerw_kernel(const float* __restrict__ theta_w,
                               const float* __restrict__ theta_b,
                               float* __restrict__ twcT, float* __restrict__ tbc) {
    __shared__ float sm[128];
    int t = threadIdx.x;  // 256 threads, one column of theta_w each
    if (t < 128) sm[t] = theta_b[t];
    __syncthreads();
    for (int st = 64; st > 0; st >>= 1) {
        if (t < st) sm[t] += sm[t + st];
        __syncthreads();
    }
    float bmean = sm[0] * (1.f / kCI);
    float m = 0.f;
    for (int k = 0; k < kCI; k++) m += theta_w[k * kC + t];
    m *= (1.f / kCI);
    for (int k = 0; k < kCI; k++) twcT[t * kCI + k] = theta_w[k * kC + t] - m;
    if (t < 128) tbc[t] = theta_b[t] - bmean;
}

// ---- Cov[b] = Xc * Xc^T  (C x C, K = N = 4096) ----------------------------
// 32x32 output tile per block, 256 threads, 2x2 per thread, K-chunks of 64.
// LDS layout [k][row] so the 2-wide row reads are float2 (ds_read_b64).
__global__ void gram_kernel(const float* __restrict__ x,
                            const float* __restrict__ xmean,
                            float* __restrict__ cov) {
    int b = blockIdx.z;
    int ci0 = blockIdx.y * 32, cj0 = blockIdx.x * 32;
    __shared__ __align__(16) float As[64][34];
    __shared__ __align__(16) float Bs[64][34];
    int tid = threadIdx.x;
    int tx = tid & 15, ty = tid >> 4;
    float a00 = 0.f, a01 = 0.f, a10 = 0.f, a11 = 0.f;
    const float* xb = x + (long)b * kC * kN;
    const float* xm = xmean + b * kC;
    for (int kc = 0; kc < kN; kc += 64) {
        __syncthreads();
        for (int l = tid; l < 2048; l += 256) {
            int k = l & 63, r = l >> 6;
            As[k][r] = xb[(long)(ci0 + r) * kN + kc + k] - xm[ci0 + r];
            Bs[k][r] = xb[(long)(cj0 + r) * kN + kc + k] - xm[cj0 + r];
        }
        __syncthreads();
#pragma unroll
        for (int k = 0; k < 64; k++) {
            float2 a = *(const float2*)&As[k][2 * ty];
            float2 bb = *(const float2*)&Bs[k][2 * tx];
            a00 += a.x * bb.x; a01 += a.x * bb.y;
            a10 += a.y * bb.x; a11 += a.y * bb.y;
        }
    }
    float* cv = cov + ((long)b * kC + ci0 + 2 * ty) * kC + cj0 + 2 * tx;
    cv[0] = a00; cv[1] = a01; cv[kC] = a10; cv[kC + 1] = a11;
}

// ---- generic batched NT gemm: C[b][m][n] = sum_k A[b][m][k] * B[b][n][k] --
// M,N multiples of 16; K multiple of 32. stride 0 => operand shared by batch.
__global__ void nt_gemm(const float* __restrict__ A, const float* __restrict__ B,
                        float* __restrict__ Cm, int M, int N, int K,
                        long sA, long sB, long sC) {
    int b = blockIdx.z;
    const float* Ab = A + (long)b * sA;
    const float* Bb = B + (long)b * sB;
    float* Cb = Cm + (long)b * sC;
    __shared__ float As[16][33];
    __shared__ float Bs[16][33];
    int tid = threadIdx.x;
    int tx = tid & 15, ty = tid >> 4;
    int m0 = blockIdx.y * 16, n0 = blockIdx.x * 16;
    float acc = 0.f;
    for (int kc = 0; kc < K; kc += 32) {
        __syncthreads();
        for (int l = tid; l < 512; l += 256) {
            int r = l >> 5, c = l & 31;
            As[r][c] = Ab[(long)(m0 + r) * K + kc + c];
            Bs[r][c] = Bb[(long)(n0 + r) * K + kc + c];
        }
        __syncthreads();
#pragma unroll
        for (int k = 0; k < 32; k++) acc += As[ty][k] * Bs[tx][k];
    }
    Cb[(long)(m0 + ty) * N + n0 + tx] = acc;
}

// ---- beta[b,o] = out_b[o] + sum_k theta_bc[k] * W2t[b,o,k] ----------------
__global__ void beta_kernel(const float* __restrict__ W2t, const float* __restrict__ tbc,
                            const float* __restrict__ out_b, float* __restrict__ beta) {
    int i = blockIdx.x * blockDim.x + threadIdx.x;  // b*kC + o
    if (i >= kB * kC) return;
    int o = i & (kC - 1);
    float s = out_b[o];
    const float* row = W2t + (long)i * kCI;
#pragma unroll 8
    for (int k = 0; k < kCI; k++) s += tbc[k] * row[k];
    beta[i] = s;
}

// ---- out[b,o,n] = x[b,o,n] + sum_c x[b,c,n]*Mt[b,o,c] + beta[b,o] ---------
// 64(o) x 64(n) tile per block, 256 threads, 4x4 per thread, K=C=256 in 16-chunks.
__global__ void final_kernel(const float* __restrict__ x, const float* __restrict__ Mt,
                             const float* __restrict__ beta, float* __restrict__ out) {
    int b = blockIdx.z;
    int o0 = blockIdx.y * 64, n0 = blockIdx.x * 64;
    __shared__ __align__(16) float Ms[16][68];  // [k][o]
    __shared__ __align__(16) float Xs[16][68];  // [k][n]
    int tid = threadIdx.x;
    int tx = tid & 15, ty = tid >> 4;
    float acc[4][4] = {};
    const float* xb = x + (long)b * kC * kN;
    const float* Mb = Mt + (long)b * kC * kC;
    for (int kc = 0; kc < kC; kc += 16) {
        __syncthreads();
        for (int l = tid; l < 1024; l += 256) {
            int c = l & 15, r = l >> 4;
            Ms[c][r] = Mb[(long)(o0 + r) * kC + kc + c];
        }
        for (int l = tid; l < 1024; l += 256) {
            int c = l & 63, r = l >> 6;
            Xs[r][c] = xb[(long)(kc + r) * kN + n0 + c];
        }
        __syncthreads();
#pragma unroll
        for (int k = 0; k < 16; k++) {
            float4 a = *(const float4*)&Ms[k][ty * 4];
            float4 bv = *(const float4*)&Xs[k][tx * 4];
            float av[4] = {a.x, a.y, a.z, a.w};
            float bw[4] = {bv.x, bv.y, bv.z, bv.w};
#pragma unroll
            for (int i = 0; i < 4; i++)
#pragma unroll
                for (int j = 0; j < 4; j++) acc[i][j] += av[i] * bw[j];
        }
    }
#pragma unroll
    for (int i = 0; i < 4; i++) {
        int o = o0 + ty * 4 + i;
        float bt = beta[b * kC + o];
        long base = (long)b * kC * kN + (long)o * kN + n0 + tx * 4;
        float4 xv = *(const float4*)(x + base);
        float4 ov;
        ov.x = acc[i][0] + xv.x + bt;
        ov.y = acc[i][1] + xv.y + bt;
        ov.z = acc[i][2] + xv.z + bt;
        ov.w = acc[i][3] + xv.w + bt;
        *(float4*)(out + base) = ov;
    }
}

extern "C" void kernel_launch(void* const* d_in, const int* in_sizes, int n_in,
                              void* d_out, int out_size, void* d_ws, size_t ws_size,
                              hipStream_t stream) {
    const float* x       = (const float*)d_in[0];
    const float* g_w     = (const float*)d_in[1];
    // d_in[2] = g_b   : mathematically cancelled (sum_n phi_c = 0)
    const float* theta_w = (const float*)d_in[3];
    const float* theta_b = (const float*)d_in[4];
    const float* phi_w   = (const float*)d_in[5];
    // d_in[6] = phi_b : cancelled by spatial centering
    const float* out_w   = (const float*)d_in[7];
    const float* out_b   = (const float*)d_in[8];
    float* out = (float*)d_out;
    float* ws  = (float*)d_ws;  // needs ~3.6 MB

    float* xmean = ws + kOffXmean;
    float* twcT  = ws + kOffTwcT;
    float* tbc   = ws + kOffTbc;
    float* cov   = ws + kOffCov;
    float* Pm    = ws + kOffP;
    float* Sm    = ws + kOffS;
    float* W2t   = ws + kOffW2t;
    float* Mt    = ws + kOffMt;
    float* beta  = ws + kOffBeta;

    xmean_kernel<<<kB * kC, 256, 0, stream>>>(x, xmean);
    centerw_kernel<<<1, 256, 0, stream>>>(theta_w, theta_b, twcT, tbc);
    gram_kernel<<<dim3(8, 8, kB), 256, 0, stream>>>(x, xmean, cov);
    // P[b] = phi_w * Cov[b]        (M=128, N=256, K=256; Cov symmetric -> NT ok)
    nt_gemm<<<dim3(16, 8, kB), 256, 0, stream>>>(phi_w, cov, Pm, kCI, kC, kC,
                                                 0, (long)kC * kC, (long)kCI * kC);
    // S[b] = P[b] * g_w^T          (M=128, N=128, K=256)
    nt_gemm<<<dim3(8, 8, kB), 256, 0, stream>>>(Pm, g_w, Sm, kCI, kCI, kC,
                                                (long)kCI * kC, 0, (long)kCI * kCI);
    // W2t[b] = out_w * S[b]^T      (M=256, N=128, K=128)
    nt_gemm<<<dim3(8, 16, kB), 256, 0, stream>>>(out_w, Sm, W2t, kC, kCI, kCI,
                                                 0, (long)kCI * kCI, (long)kC * kCI);
    // Mt[b] = W2t[b] * theta_wc    (M=256, N=256, K=128)
    nt_gemm<<<dim3(16, 16, kB), 256, 0, stream>>>(W2t, twcT, Mt, kC, kC, kCI,
                                                  (long)kC * kCI, 0, (long)kC * kC);
    beta_kernel<<<kB, 256, 0, stream>>>(W2t, tbc, out_b, beta);
    final_kernel<<<dim3(kN / 64, kC / 64, kB), 256, 0, stream>>>(x, Mt, beta, out);
}

// Round 2
// 367.759 us; speedup vs baseline: 1.0874x; 1.0874x over previous
//
#include <hip/hip_runtime.h>

// Problem constants (B, C, CI, H, W) = (4, 256, 128, 64, 64)
constexpr int kB  = 4;
constexpr int kC  = 256;
constexpr int kCI = 128;
constexpr int kN  = 64 * 64;  // 4096

// ---------------------------------------------------------------------------
// Algebraic collapse (no gram, no pairwise):
//   Phi = phi_w*X, G2 = g_w*X                (CI x N each; stacked as PG, 2C... rows)
//   T   = Phic*G2^T = Phi*G2^T - rsPhi*rsG2^T/N     (CI x CI per batch)
//   W2t = out_w * T^T                        (C x CI)
//   Mt  = W2t * theta_wc                     (C x C), theta_wc col-centered
//   beta= W2t * theta_bc + out_b
//   out[b,o,n] = x[b,o,n] + sum_c Mt[b,o,c]*x[b,c,n] + beta[b,o]
// g_b drops (rows of Phic sum to 0); phi_b drops (spatial centering).
// ---------------------------------------------------------------------------

// ws layout (floats)
constexpr long kOffTwcT = 0;                          // kC*kCI        = 32768
constexpr long kOffTbc  = kOffTwcT + kC * kCI;        // kCI           = 128
constexpr long kOffPG   = kOffTbc + kCI;              // kB*kC*kN      = 4194304
constexpr long kOffRs   = kOffPG + (long)kB * kC * kN;// kB*kC         = 1024
constexpr long kOffT    = kOffRs + kB * kC;           // kB*kCI*kCI    = 65536
constexpr long kOffW2t  = kOffT + kB * kCI * kCI;     // kB*kC*kCI     = 131072
constexpr long kOffMt   = kOffW2t + kB * kC * kCI;    // kB*kC*kC      = 262144
constexpr long kOffBeta = kOffMt + kB * kC * kC;      // kB*kC         = 1024
// total ~4.69M floats = 18.8 MB of d_ws

// ---- theta_w column-centered (transposed) + theta_b centered --------------
__global__ void centerw_kernel(const float* __restrict__ theta_w,
                               const float* __restrict__ theta_b,
                               float* __restrict__ twcT, float* __restrict__ tbc) {
    __shared__ float sm[128];
    int t = threadIdx.x;  // 256 threads, one column of theta_w each
    if (t < 128) sm[t] = theta_b[t];
    __syncthreads();
    for (int st = 64; st > 0; st >>= 1) {
        if (t < st) sm[t] += sm[t + st];
        __syncthreads();
    }
    float bmean = sm[0] * (1.f / kCI);
    float m = 0.f;
    for (int k = 0; k < kCI; k++) m += theta_w[k * kC + t];
    m *= (1.f / kCI);
    for (int k = 0; k < kCI; k++) twcT[t * kCI + k] = theta_w[k * kC + t] - m;
    if (t < 128) tbc[t] = theta_b[t] - bmean;
}

// ---- PG[b][r][n]: r<128 -> phi_w row r; r>=128 -> g_w row r-128 -----------
// 128(M) x 64(N) tile, 256 threads, 8x4 per thread, K=kC in chunks of 16.
__global__ void pg_gemm(const float* __restrict__ phi_w, const float* __restrict__ g_w,
                        const float* __restrict__ x, float* __restrict__ PG) {
    int b = blockIdx.z;
    int m0 = blockIdx.y * 128, n0 = blockIdx.x * 64;
    __shared__ __align__(16) float Ws[16][136];  // [k][row]
    __shared__ __align__(16) float Xs[16][68];   // [k][col]
    int t = threadIdx.x;
    int tx = t & 15, ty = t >> 4;
    float acc[8][4] = {};
    const float* xb = x + (long)b * kC * kN;
    for (int kc = 0; kc < kC; kc += 16) {
        __syncthreads();
        {   // W tile: 128 rows x 16 cols
            int r = t >> 2, c4 = (t & 3) * 4;
#pragma unroll
            for (int i = 0; i < 2; i++) {
                int rr = r + 64 * i;
                int row = m0 + rr;
                const float* wr = (row < kCI) ? (phi_w + (long)row * kC)
                                              : (g_w + (long)(row - kCI) * kC);
                float4 v = *(const float4*)(wr + kc + c4);
                Ws[c4 + 0][rr] = v.x; Ws[c4 + 1][rr] = v.y;
                Ws[c4 + 2][rr] = v.z; Ws[c4 + 3][rr] = v.w;
            }
        }
        {   // X tile: 16 rows(k) x 64 cols
            int k = t >> 4, c4 = (t & 15) * 4;
            *(float4*)&Xs[k][c4] = *(const float4*)(xb + (long)(kc + k) * kN + n0 + c4);
        }
        __syncthreads();
#pragma unroll
        for (int k = 0; k < 16; k++) {
            float4 a0 = *(const float4*)&Ws[k][8 * ty];
            float4 a1 = *(const float4*)&Ws[k][8 * ty + 4];
            float4 bv = *(const float4*)&Xs[k][4 * tx];
            float av[8] = {a0.x, a0.y, a0.z, a0.w, a1.x, a1.y, a1.z, a1.w};
            float bw[4] = {bv.x, bv.y, bv.z, bv.w};
#pragma unroll
            for (int i = 0; i < 8; i++)
#pragma unroll
                for (int j = 0; j < 4; j++) acc[i][j] += av[i] * bw[j];
        }
    }
    float* pb = PG + (long)b * kC * kN;
#pragma unroll
    for (int i = 0; i < 8; i++) {
        int row = m0 + ty * 8 + i;
        float4 ov = {acc[i][0], acc[i][1], acc[i][2], acc[i][3]};
        *(float4*)(pb + (long)row * kN + n0 + tx * 4) = ov;
    }
}

// ---- rs[b][r] = sum over n of PG[b][r][n] ---------------------------------
__global__ void rowsum_kernel(const float* __restrict__ PG, float* __restrict__ rs) {
    int br = blockIdx.x;  // 0 .. kB*kC-1
    const float* p = PG + (long)br * kN;
    float s = 0.f;
    for (int i = threadIdx.x * 4; i < kN; i += 1024) {
        float4 v = *(const float4*)(p + i);
        s += v.x + v.y + v.z + v.w;
    }
    __shared__ float sm[256];
    sm[threadIdx.x] = s;
    __syncthreads();
    for (int st = 128; st > 0; st >>= 1) {
        if (threadIdx.x < st) sm[threadIdx.x] += sm[threadIdx.x + st];
        __syncthreads();
    }
    if (threadIdx.x == 0) rs[br] = sm[0];
}

// ---- T[b] += split-K partial of Phi*G2^T (s==0 block adds -rsPhi*rsG2^T/N)-
// One 128x128 tile per (b, slice); slice covers 64 of the 4096 m's.
constexpr int kSplits = 64;
__global__ void tsplit_kernel(const float* __restrict__ PG, const float* __restrict__ rs,
                              float* __restrict__ T) {
    int s = blockIdx.x, b = blockIdx.z;
    int mbase = s * (kN / kSplits);  // 64 m's per slice
    __shared__ __align__(16) float As[16][136];  // [m][c]   (Phi rows)
    __shared__ __align__(16) float Bs[16][136];  // [m][c']  (G2 rows)
    int t = threadIdx.x;
    int tx = t & 15, ty = t >> 4;
    float acc[8][8] = {};
    const float* Phi = PG + (long)b * kC * kN;          // rows 0..127
    const float* G2  = PG + (long)b * kC * kN + (long)kCI * kN;  // rows 128..255
    for (int mc = 0; mc < kN / kSplits; mc += 16) {
        __syncthreads();
        {   // each operand: 128 rows x 16 m
            int r = t >> 2, c4 = (t & 3) * 4;
#pragma unroll
            for (int i = 0; i < 2; i++) {
                int rr = r + 64 * i;
                float4 va = *(const float4*)(Phi + (long)rr * kN + mbase + mc + c4);
                As[c4 + 0][rr] = va.x; As[c4 + 1][rr] = va.y;
                As[c4 + 2][rr] = va.z; As[c4 + 3][rr] = va.w;
                float4 vb = *(const float4*)(G2 + (long)rr * kN + mbase + mc + c4);
                Bs[c4 + 0][rr] = vb.x; Bs[c4 + 1][rr] = vb.y;
                Bs[c4 + 2][rr] = vb.z; Bs[c4 + 3][rr] = vb.w;
            }
        }
        __syncthreads();
#pragma unroll
        for (int k = 0; k < 16; k++) {
            float4 a0 = *(const float4*)&As[k][8 * ty];
            float4 a1 = *(const float4*)&As[k][8 * ty + 4];
            float4 b0 = *(const float4*)&Bs[k][8 * tx];
            float4 b1 = *(const float4*)&Bs[k][8 * tx + 4];
            float av[8] = {a0.x, a0.y, a0.z, a0.w, a1.x, a1.y, a1.z, a1.w};
            float bw[8] = {b0.x, b0.y, b0.z, b0.w, b1.x, b1.y, b1.z, b1.w};
#pragma unroll
            for (int i = 0; i < 8; i++)
#pragma unroll
                for (int j = 0; j < 8; j++) acc[i][j] += av[i] * bw[j];
        }
    }
    const float* rsb = rs + b * kC;
    float* Tb = T + (long)b * kCI * kCI;
#pragma unroll
    for (int i = 0; i < 8; i++) {
        int c = ty * 8 + i;
#pragma unroll
        for (int j = 0; j < 8; j++) {
            int cp = tx * 8 + j;
            float v = acc[i][j];
            if (s == 0) v -= rsb[c] * rsb[kCI + cp] * (1.f / kN);
            atomicAdd(Tb + (long)c * kCI + cp, v);
        }
    }
}

// ---- NT gemm, 64x64 tile, 4x4/thread: C[b][m][n] = sum_k A[b][m][k]*B[b][n][k]
__global__ void nt64_gemm(const float* __restrict__ A, const float* __restrict__ B,
                          float* __restrict__ Cm, int M, int N, int K,
                          long sA, long sB, long sC) {
    int b = blockIdx.z;
    const float* Ab = A + (long)b * sA;
    const float* Bb = B + (long)b * sB;
    float* Cb = Cm + (long)b * sC;
    __shared__ __align__(16) float As[16][68];  // [k][row]
    __shared__ __align__(16) float Bs[16][68];
    int t = threadIdx.x;
    int tx = t & 15, ty = t >> 4;
    int m0 = blockIdx.y * 64, n0 = blockIdx.x * 64;
    float acc[4][4] = {};
    for (int kc = 0; kc < K; kc += 16) {
        __syncthreads();
        {
            int r = t >> 2, c4 = (t & 3) * 4;
            float4 va = *(const float4*)(Ab + (long)(m0 + r) * K + kc + c4);
            As[c4 + 0][r] = va.x; As[c4 + 1][r] = va.y;
            As[c4 + 2][r] = va.z; As[c4 + 3][r] = va.w;
            float4 vb = *(const float4*)(Bb + (long)(n0 + r) * K + kc + c4);
            Bs[c4 + 0][r] = vb.x; Bs[c4 + 1][r] = vb.y;
            Bs[c4 + 2][r] = vb.z; Bs[c4 + 3][r] = vb.w;
        }
        __syncthreads();
#pragma unroll
        for (int k = 0; k < 16; k++) {
            float4 a = *(const float4*)&As[k][4 * ty];
            float4 bv = *(const float4*)&Bs[k][4 * tx];
            float av[4] = {a.x, a.y, a.z, a.w};
            float bw[4] = {bv.x, bv.y, bv.z, bv.w};
#pragma unroll
            for (int i = 0; i < 4; i++)
#pragma unroll
                for (int j = 0; j < 4; j++) acc[i][j] += av[i] * bw[j];
        }
    }
#pragma unroll
    for (int i = 0; i < 4; i++) {
        float4 ov = {acc[i][0], acc[i][1], acc[i][2], acc[i][3]};
        *(float4*)(Cb + (long)(m0 + 4 * ty + i) * N + n0 + 4 * tx) = ov;
    }
}

// ---- beta[b,o] = out_b[o] + sum_k theta_bc[k] * W2t[b,o,k] ----------------
__global__ void beta_kernel(const float* __restrict__ W2t, const float* __restrict__ tbc,
                            const float* __restrict__ out_b, float* __restrict__ beta) {
    int i = blockIdx.x * blockDim.x + threadIdx.x;  // b*kC + o
    if (i >= kB * kC) return;
    int o = i & (kC - 1);
    float s = out_b[o];
    const float* row = W2t + (long)i * kCI;
#pragma unroll 8
    for (int k = 0; k < kCI; k++) s += tbc[k] * row[k];
    beta[i] = s;
}

// ---- out[b,o,n] = x[b,o,n] + sum_c Mt[b,o,c]*x[b,c,n] + beta[b,o] ---------
// 128(o) x 64(n) tile, 256 threads, 8x4 per thread, K=kC in chunks of 16.
__global__ void final_kernel(const float* __restrict__ x, const float* __restrict__ Mt,
                             const float* __restrict__ beta, float* __restrict__ out) {
    int b = blockIdx.z;
    int o0 = blockIdx.y * 128, n0 = blockIdx.x * 64;
    __shared__ __align__(16) float Ms[16][136];  // [k][o-row]
    __shared__ __align__(16) float Xs[16][68];   // [k][n-col]
    int t = threadIdx.x;
    int tx = t & 15, ty = t >> 4;
    float acc[8][4] = {};
    const float* xb = x + (long)b * kC * kN;
    const float* Mb = Mt + (long)b * kC * kC;
    for (int kc = 0; kc < kC; kc += 16) {
        __syncthreads();
        {   // Mt tile: 128 rows x 16 cols
            int r = t >> 2, c4 = (t & 3) * 4;
#pragma unroll
            for (int i = 0; i < 2; i++) {
                int rr = r + 64 * i;
                float4 v = *(const float4*)(Mb + (long)(o0 + rr) * kC + kc + c4);
                Ms[c4 + 0][rr] = v.x; Ms[c4 + 1][rr] = v.y;
                Ms[c4 + 2][rr] = v.z; Ms[c4 + 3][rr] = v.w;
            }
        }
        {   // X tile: 16 rows(ch) x 64 cols
            int k = t >> 4, c4 = (t & 15) * 4;
            *(float4*)&Xs[k][c4] = *(const float4*)(xb + (long)(kc + k) * kN + n0 + c4);
        }
        __syncthreads();
#pragma unroll
        for (int k = 0; k < 16; k++) {
            float4 a0 = *(const float4*)&Ms[k][8 * ty];
            float4 a1 = *(const float4*)&Ms[k][8 * ty + 4];
            float4 bv = *(const float4*)&Xs[k][4 * tx];
            float av[8] = {a0.x, a0.y, a0.z, a0.w, a1.x, a1.y, a1.z, a1.w};
            float bw[4] = {bv.x, bv.y, bv.z, bv.w};
#pragma unroll
            for (int i = 0; i < 8; i++)
#pragma unroll
                for (int j = 0; j < 4; j++) acc[i][j] += av[i] * bw[j];
        }
    }
#pragma unroll
    for (int i = 0; i < 8; i++) {
        int o = o0 + ty * 8 + i;
        float bt = beta[b * kC + o];
        long base = (long)b * kC * kN + (long)o * kN + n0 + tx * 4;
        float4 xv = *(const float4*)(x + base);
        float4 ov = {acc[i][0] + xv.x + bt, acc[i][1] + xv.y + bt,
                     acc[i][2] + xv.z + bt, acc[i][3] + xv.w + bt};
        *(float4*)(out + base) = ov;
    }
}

extern "C" void kernel_launch(void* const* d_in, const int* in_sizes, int n_in,
                              void* d_out, int out_size, void* d_ws, size_t ws_size,
                              hipStream_t stream) {
    const float* x       = (const float*)d_in[0];
    const float* g_w     = (const float*)d_in[1];
    // d_in[2] = g_b   : cancelled (rows of Phic sum to 0)
    const float* theta_w = (const float*)d_in[3];
    const float* theta_b = (const float*)d_in[4];
    const float* phi_w   = (const float*)d_in[5];
    // d_in[6] = phi_b : cancelled by spatial centering
    const float* out_w   = (const float*)d_in[7];
    const float* out_b   = (const float*)d_in[8];
    float* out = (float*)d_out;
    float* ws  = (float*)d_ws;  // needs ~18.8 MB

    float* twcT = ws + kOffTwcT;
    float* tbc  = ws + kOffTbc;
    float* PG   = ws + kOffPG;
    float* rs   = ws + kOffRs;
    float* T    = ws + kOffT;
    float* W2t  = ws + kOffW2t;
    float* Mt   = ws + kOffMt;
    float* beta = ws + kOffBeta;

    hipMemsetAsync(T, 0, (size_t)kB * kCI * kCI * sizeof(float), stream);
    centerw_kernel<<<1, 256, 0, stream>>>(theta_w, theta_b, twcT, tbc);
    // PG[b] = [phi_w; g_w] * X[b]   (256 x 4096, K=256)
    pg_gemm<<<dim3(kN / 64, 2, kB), 256, 0, stream>>>(phi_w, g_w, x, PG);
    rowsum_kernel<<<kB * kC, 256, 0, stream>>>(PG, rs);
    // T[b] = Phic * G2^T            (128 x 128, K=4096, split-K + atomics)
    tsplit_kernel<<<dim3(kSplits, 1, kB), 256, 0, stream>>>(PG, rs, T);
    // W2t[b] = out_w * T[b]^T       (M=256, N=128, K=128)
    nt64_gemm<<<dim3(2, 4, kB), 256, 0, stream>>>(out_w, T, W2t, kC, kCI, kCI,
                                                  0, (long)kCI * kCI, (long)kC * kCI);
    // Mt[b] = W2t[b] * theta_wc     (M=256, N=256, K=128)
    nt64_gemm<<<dim3(4, 4, kB), 256, 0, stream>>>(W2t, twcT, Mt, kC, kC, kCI,
                                                  (long)kC * kCI, 0, (long)kC * kC);
    beta_kernel<<<kB, 256, 0, stream>>>(W2t, tbc, out_b, beta);
    final_kernel<<<dim3(kN / 64, 2, kB), 256, 0, stream>>>(x, Mt, beta, out);
}